// Round 1
// baseline (506.719 us; speedup 1.0000x reference)
//
#include <hip/hip_runtime.h>

typedef unsigned short u16;
typedef __bf16 bf16x8_t __attribute__((ext_vector_type(8)));
typedef float  f32x4_t  __attribute__((ext_vector_type(4)));
typedef u16    us8_t    __attribute__((ext_vector_type(8)));
typedef u16    us4_t    __attribute__((ext_vector_type(4)));

__device__ __forceinline__ u16 f2bf(float f) {
    __bf16 h = (__bf16)f;
    return __builtin_bit_cast(u16, h);
}
__device__ __forceinline__ bf16x8_t ld_bf8(const u16* p) {
    us8_t u = *(const us8_t*)p;
    return __builtin_bit_cast(bf16x8_t, u);
}
__device__ __forceinline__ f32x4_t mfma16(bf16x8_t a, bf16x8_t b, f32x4_t c) {
    return __builtin_amdgcn_mfma_f32_16x16x32_bf16(a, b, c, 0, 0, 0);
}

// ---------------- weight transpose+convert: fp32 [k][n] -> bf16 [n][k] ----------------
__global__ __launch_bounds__(256) void transpose_w_kernel(
    const float* __restrict__ w0, const float* __restrict__ w1,
    const float* __restrict__ w2, const float* __restrict__ w3,
    u16* __restrict__ out)
{
    __shared__ u16 t[64][65];
    const int z = blockIdx.z;
    const float* src = (z == 0) ? w0 : (z == 1) ? w1 : (z == 2) ? w2 : w3;
    u16* dst = out + (size_t)z * 1024 * 1024;
    const int bk = blockIdx.x * 64, bn = blockIdx.y * 64;
    const int tid = threadIdx.x;
    const int r = tid >> 2, c4 = tid & 3;
    for (int i = 0; i < 4; i++) {
        float4 v = *(const float4*)(src + (size_t)(bk + r) * 1024 + bn + c4 * 16 + i * 4);
        t[r][c4 * 16 + i * 4 + 0] = f2bf(v.x);
        t[r][c4 * 16 + i * 4 + 1] = f2bf(v.y);
        t[r][c4 * 16 + i * 4 + 2] = f2bf(v.z);
        t[r][c4 * 16 + i * 4 + 3] = f2bf(v.w);
    }
    __syncthreads();
    for (int i = 0; i < 2; i++) {
        us8_t w;
        for (int j = 0; j < 8; j++) w[j] = t[c4 * 16 + i * 8 + j][r];
        *(us8_t*)(dst + (size_t)(bn + r) * 1024 + bk + c4 * 16 + i * 8) = w;
    }
}

// ---------------- mask pack: int32 [B,1,S,S] -> 1 bit per key ----------------
__global__ __launch_bounds__(256) void pack_mask_kernel(
    const int* __restrict__ mask, unsigned* __restrict__ mp)
{
    const int w = blockIdx.x * 256 + threadIdx.x;   // word idx, 2*2048*64 total
    const int* src = mask + (size_t)w * 32;
    unsigned bits = 0u;
    for (int i = 0; i < 32; i += 4) {
        int4 v = *(const int4*)(src + i);
        bits |= (unsigned)(v.x != 0) << (i + 0);
        bits |= (unsigned)(v.y != 0) << (i + 1);
        bits |= (unsigned)(v.z != 0) << (i + 2);
        bits |= (unsigned)(v.w != 0) << (i + 3);
    }
    mp[w] = bits;
}

// ---------------- GEMM: Y[4096,1024] = X @ Wt^T + bias ----------------
// AT: float (convert in staging) or u16 (bf16). MODE 0: bf16 out; 1: fp32 out; 2: bf16 transposed Vt out.
template <typename AT, int MODE>
__global__ __launch_bounds__(256) void gemm_kernel(
    const AT* __restrict__ X, const u16* __restrict__ Wt,
    const float* __restrict__ bias, void* __restrict__ Yv)
{
    constexpr int K = 1024;
    __shared__ u16 As[128 * 32];
    __shared__ u16 Bs[64 * 32];
    const int m0 = blockIdx.x * 128, n0 = blockIdx.y * 64;
    const int tid = threadIdx.x;
    const int lane = tid & 63, wave = tid >> 6;
    const int l15 = lane & 15, quad = lane >> 4;
    const int wm = (wave & 1) * 64, wn = (wave >> 1) * 32;

    const f32x4_t z4 = {0.f, 0.f, 0.f, 0.f};
    f32x4_t acc[4][2];
    for (int i = 0; i < 4; i++) for (int j = 0; j < 2; j++) acc[i][j] = z4;

    const int ar = tid >> 1, ah = tid & 1;
    const int br = tid >> 2, bc = tid & 3;

    for (int k0 = 0; k0 < K; k0 += 32) {
        if constexpr (sizeof(AT) == 4) {
            const float* s = (const float*)X + (size_t)(m0 + ar) * K + k0 + ah * 16;
            us8_t t0, t1;
            {
                float4 v = *(const float4*)(s + 0);
                t0[0] = f2bf(v.x); t0[1] = f2bf(v.y); t0[2] = f2bf(v.z); t0[3] = f2bf(v.w);
                float4 w = *(const float4*)(s + 4);
                t0[4] = f2bf(w.x); t0[5] = f2bf(w.y); t0[6] = f2bf(w.z); t0[7] = f2bf(w.w);
            }
            {
                float4 v = *(const float4*)(s + 8);
                t1[0] = f2bf(v.x); t1[1] = f2bf(v.y); t1[2] = f2bf(v.z); t1[3] = f2bf(v.w);
                float4 w = *(const float4*)(s + 12);
                t1[4] = f2bf(w.x); t1[5] = f2bf(w.y); t1[6] = f2bf(w.z); t1[7] = f2bf(w.w);
            }
            *(us8_t*)&As[ar * 32 + ah * 16 + 0] = t0;
            *(us8_t*)&As[ar * 32 + ah * 16 + 8] = t1;
        } else {
            const u16* s = (const u16*)X + (size_t)(m0 + ar) * K + k0 + ah * 16;
            *(us8_t*)&As[ar * 32 + ah * 16 + 0] = *(const us8_t*)(s + 0);
            *(us8_t*)&As[ar * 32 + ah * 16 + 8] = *(const us8_t*)(s + 8);
        }
        {
            const u16* s = Wt + (size_t)(n0 + br) * K + k0 + bc * 8;
            *(us8_t*)&Bs[br * 32 + bc * 8] = *(const us8_t*)s;
        }
        __syncthreads();
        bf16x8_t af[4], bfr[2];
        for (int i = 0; i < 4; i++) af[i] = ld_bf8(&As[(wm + i * 16 + l15) * 32 + quad * 8]);
        for (int j = 0; j < 2; j++) bfr[j] = ld_bf8(&Bs[(wn + j * 16 + l15) * 32 + quad * 8]);
        for (int i = 0; i < 4; i++)
            for (int j = 0; j < 2; j++)
                acc[i][j] = mfma16(af[i], bfr[j], acc[i][j]);
        __syncthreads();
    }

    for (int i = 0; i < 4; i++) {
        const int gmb = m0 + wm + i * 16 + quad * 4;
        for (int j = 0; j < 2; j++) {
            const int gn = n0 + wn + j * 16 + l15;
            const float bb = bias[gn];
            if constexpr (MODE == 0) {
                u16* Y = (u16*)Yv;
                for (int r = 0; r < 4; r++)
                    Y[(size_t)(gmb + r) * 1024 + gn] = f2bf(acc[i][j][r] + bb);
            } else if constexpr (MODE == 1) {
                float* Y = (float*)Yv;
                for (int r = 0; r < 4; r++)
                    Y[(size_t)(gmb + r) * 1024 + gn] = acc[i][j][r] + bb;
            } else {
                // transposed store into Vt[bh][d][s]: flat = (b*1024+gn)*2048 + s
                u16* Y = (u16*)Yv;
                const int bb_idx = gmb >> 11, s = gmb & 2047;
                us4_t w;
                for (int r = 0; r < 4; r++) w[r] = f2bf(acc[i][j][r] + bb);
                *(us4_t*)&Y[((size_t)(bb_idx * 1024 + gn)) * 2048 + s] = w;
            }
        }
    }
}

// ---------------- flash attention ----------------
// grid: (h=16, qb=32, b=2), 256 thr = 4 waves, wave handles 16 q rows, 32-key tiles
__global__ __launch_bounds__(256) void attn_kernel(
    const u16* __restrict__ Q, const u16* __restrict__ Kb,
    const u16* __restrict__ Vt, const unsigned* __restrict__ mp,
    u16* __restrict__ C)
{
    const int h = blockIdx.x, qb = blockIdx.y, b = blockIdx.z;
    const int tid = threadIdx.x, lane = tid & 63, wave = tid >> 6;
    const int l15 = lane & 15, quad = lane >> 4;
    const int q0 = qb * 64 + wave * 16;
    const int grow = b * 2048 + q0;

    __shared__ u16 Pl[4][16 * 32];

    bf16x8_t aq[2];
    for (int ks = 0; ks < 2; ks++)
        aq[ks] = ld_bf8(Q + (size_t)(grow + l15) * 1024 + h * 64 + ks * 32 + quad * 8);

    const f32x4_t z4 = {0.f, 0.f, 0.f, 0.f};
    f32x4_t o[4];
    for (int i = 0; i < 4; i++) o[i] = z4;
    float mrow[4], lrow[4];
    for (int r = 0; r < 4; r++) { mrow[r] = -__builtin_inff(); lrow[r] = 0.f; }

    const u16* Kbase = Kb + (size_t)(b * 2048) * 1024 + h * 64;
    const u16* Vbase = Vt + ((size_t)(b * 16 + h) * 64) * 2048;
    const unsigned* mbase = mp + (size_t)(b * 2048 + q0 + quad * 4) * 64;

    for (int kt = 0; kt < 64; ++kt) {
        const int kbase = kt * 32;
        bf16x8_t bk[2][2];
        for (int s = 0; s < 2; s++)
            for (int ks = 0; ks < 2; ks++)
                bk[s][ks] = ld_bf8(Kbase + (size_t)(kbase + s * 16 + l15) * 1024 + ks * 32 + quad * 8);
        f32x4_t sc0 = z4, sc1 = z4;
        sc0 = mfma16(aq[0], bk[0][0], sc0);
        sc0 = mfma16(aq[1], bk[0][1], sc0);
        sc1 = mfma16(aq[0], bk[1][0], sc1);
        sc1 = mfma16(aq[1], bk[1][1], sc1);

        for (int r = 0; r < 4; r++) {
            const unsigned mw = mbase[r * 64 + kt];
            float v0 = sc0[r] * 0.125f; if ((mw >> l15) & 1u) v0 -= 1e9f;
            float v1 = sc1[r] * 0.125f; if ((mw >> (16 + l15)) & 1u) v1 -= 1e9f;
            float x = fmaxf(v0, v1);
            for (int off = 1; off < 16; off <<= 1) x = fmaxf(x, __shfl_xor(x, off));
            const float mnew = fmaxf(mrow[r], x);
            const float alpha = __expf(mrow[r] - mnew);
            const float p0 = __expf(v0 - mnew);
            const float p1 = __expf(v1 - mnew);
            float ssum = p0 + p1;
            for (int off = 1; off < 16; off <<= 1) ssum += __shfl_xor(ssum, off);
            mrow[r] = mnew;
            lrow[r] = lrow[r] * alpha + ssum;
            for (int nt = 0; nt < 4; nt++) o[nt][r] *= alpha;
            Pl[wave][(quad * 4 + r) * 32 + l15]      = f2bf(p0);
            Pl[wave][(quad * 4 + r) * 32 + 16 + l15] = f2bf(p1);
        }
        __syncthreads();
        bf16x8_t ap = ld_bf8(&Pl[wave][l15 * 32 + quad * 8]);
        for (int nt = 0; nt < 4; nt++) {
            bf16x8_t bv = ld_bf8(Vbase + (size_t)(nt * 16 + l15) * 2048 + kbase + quad * 8);
            o[nt] = mfma16(ap, bv, o[nt]);
        }
        __syncthreads();
    }

    for (int r = 0; r < 4; r++) {
        const float invl = 1.0f / lrow[r];
        for (int nt = 0; nt < 4; nt++)
            C[(size_t)(grow + quad * 4 + r) * 1024 + h * 64 + nt * 16 + l15] = f2bf(o[nt][r] * invl);
    }
}

extern "C" void kernel_launch(void* const* d_in, const int* in_sizes, int n_in,
                              void* d_out, int out_size, void* d_ws, size_t ws_size,
                              hipStream_t stream) {
    const float* q    = (const float*)d_in[0];
    const float* k    = (const float*)d_in[1];
    const float* v    = (const float*)d_in[2];
    const int*   mask = (const int*)d_in[3];
    const float* wq   = (const float*)d_in[4];
    const float* bq   = (const float*)d_in[5];
    const float* wk   = (const float*)d_in[6];
    const float* bk   = (const float*)d_in[7];
    const float* wv   = (const float*)d_in[8];
    const float* bv   = (const float*)d_in[9];
    const float* wo   = (const float*)d_in[10];
    const float* bo   = (const float*)d_in[11];
    float* out = (float*)d_out;

    char* ws = (char*)d_ws;
    const size_t MB = 1ull << 20;
    u16* Wt      = (u16*)(ws);             // 4 x 2 MB (bf16 [n][k] per weight)
    u16* Qb      = (u16*)(ws + 8 * MB);    // 8 MB
    u16* Kbw     = (u16*)(ws + 16 * MB);   // 8 MB
    u16* Vtw     = (u16*)(ws + 24 * MB);   // 8 MB (transposed [bh][d][s])
    u16* CT      = (u16*)(ws + 32 * MB);   // 8 MB
    unsigned* mp = (unsigned*)(ws + 40 * MB); // 1 MB

    transpose_w_kernel<<<dim3(16, 16, 4), 256, 0, stream>>>(wq, wk, wv, wo, Wt);
    pack_mask_kernel<<<dim3(1024), 256, 0, stream>>>(mask, mp);

    const size_t WSTRIDE = 1024 * 1024;
    gemm_kernel<float, 0><<<dim3(32, 16), 256, 0, stream>>>(q, Wt + 0 * WSTRIDE, bq, Qb);
    gemm_kernel<float, 0><<<dim3(32, 16), 256, 0, stream>>>(k, Wt + 1 * WSTRIDE, bk, Kbw);
    gemm_kernel<float, 2><<<dim3(32, 16), 256, 0, stream>>>(v, Wt + 2 * WSTRIDE, bv, Vtw);

    attn_kernel<<<dim3(16, 32, 2), 256, 0, stream>>>(Qb, Kbw, Vtw, mp, CT);

    gemm_kernel<u16, 1><<<dim3(32, 16), 256, 0, stream>>>(CT, Wt + 3 * WSTRIDE, bo, out);
}

// Round 2
// 476.382 us; speedup vs baseline: 1.0637x; 1.0637x over previous
//
#include <hip/hip_runtime.h>

typedef unsigned short u16;
typedef __bf16 bf16x8_t __attribute__((ext_vector_type(8)));
typedef float  f32x4_t  __attribute__((ext_vector_type(4)));
typedef u16    us8_t    __attribute__((ext_vector_type(8)));
typedef u16    us4_t    __attribute__((ext_vector_type(4)));

__device__ __forceinline__ u16 f2bf(float f) {
    __bf16 h = (__bf16)f;
    return __builtin_bit_cast(u16, h);
}
__device__ __forceinline__ bf16x8_t ld_bf8(const u16* p) {
    us8_t u = *(const us8_t*)p;
    return __builtin_bit_cast(bf16x8_t, u);
}
__device__ __forceinline__ f32x4_t mfma16(bf16x8_t a, bf16x8_t b, f32x4_t c) {
    return __builtin_amdgcn_mfma_f32_16x16x32_bf16(a, b, c, 0, 0, 0);
}

// ---------------- weight transpose+convert: fp32 [k][n] -> bf16 [n][k] ----------------
__global__ __launch_bounds__(256) void transpose_w_kernel(
    const float* __restrict__ w0, const float* __restrict__ w1,
    const float* __restrict__ w2, const float* __restrict__ w3,
    u16* __restrict__ out)
{
    __shared__ u16 t[64][65];
    const int z = blockIdx.z;
    const float* src = (z == 0) ? w0 : (z == 1) ? w1 : (z == 2) ? w2 : w3;
    u16* dst = out + (size_t)z * 1024 * 1024;
    const int bk = blockIdx.x * 64, bn = blockIdx.y * 64;
    const int tid = threadIdx.x;
    const int r = tid >> 2, c4 = tid & 3;
    for (int i = 0; i < 4; i++) {
        float4 v = *(const float4*)(src + (size_t)(bk + r) * 1024 + bn + c4 * 16 + i * 4);
        t[r][c4 * 16 + i * 4 + 0] = f2bf(v.x);
        t[r][c4 * 16 + i * 4 + 1] = f2bf(v.y);
        t[r][c4 * 16 + i * 4 + 2] = f2bf(v.z);
        t[r][c4 * 16 + i * 4 + 3] = f2bf(v.w);
    }
    __syncthreads();
    for (int i = 0; i < 2; i++) {
        us8_t w;
        for (int j = 0; j < 8; j++) w[j] = t[c4 * 16 + i * 8 + j][r];
        *(us8_t*)(dst + (size_t)(bn + r) * 1024 + bk + c4 * 16 + i * 8) = w;
    }
}

// ---------------- mask pack: int32 [B,1,S,S] -> 1 bit per key ----------------
__global__ __launch_bounds__(256) void pack_mask_kernel(
    const int* __restrict__ mask, unsigned* __restrict__ mp)
{
    const int w = blockIdx.x * 256 + threadIdx.x;   // word idx, 2*2048*64 total
    const int* src = mask + (size_t)w * 32;
    unsigned bits = 0u;
    for (int i = 0; i < 32; i += 4) {
        int4 v = *(const int4*)(src + i);
        bits |= (unsigned)(v.x != 0) << (i + 0);
        bits |= (unsigned)(v.y != 0) << (i + 1);
        bits |= (unsigned)(v.z != 0) << (i + 2);
        bits |= (unsigned)(v.w != 0) << (i + 3);
    }
    mp[w] = bits;
}

// ---------------- fused QKV projection GEMM ----------------
// z=0: Q (bf16 [s][d]), z=1: K (bf16 [s][d]), z=2: V stored transposed Vt[bh][d][s]
__global__ __launch_bounds__(256) void qkv_gemm_kernel(
    const float* __restrict__ qi, const float* __restrict__ ki, const float* __restrict__ vi,
    const u16* __restrict__ Wt,
    const float* __restrict__ bqv, const float* __restrict__ bkv, const float* __restrict__ bvv,
    u16* __restrict__ Qo, u16* __restrict__ Ko, u16* __restrict__ Vo)
{
    constexpr int K = 1024;
    __shared__ u16 As[128 * 32];
    __shared__ u16 Bs[64 * 32];
    const int z = blockIdx.z;
    const float* X = (z == 0) ? qi : (z == 1) ? ki : vi;
    const u16* W = Wt + (size_t)z * 1024 * 1024;
    const float* bias = (z == 0) ? bqv : (z == 1) ? bkv : bvv;

    const int m0 = blockIdx.x * 128, n0 = blockIdx.y * 64;
    const int tid = threadIdx.x;
    const int lane = tid & 63, wave = tid >> 6;
    const int l15 = lane & 15, quad = lane >> 4;
    const int wm = (wave & 1) * 64, wn = (wave >> 1) * 32;

    const f32x4_t z4 = {0.f, 0.f, 0.f, 0.f};
    f32x4_t acc[4][2];
    for (int i = 0; i < 4; i++) for (int j = 0; j < 2; j++) acc[i][j] = z4;

    const int ar = tid >> 1, ah = tid & 1;
    const int br = tid >> 2, bc = tid & 3;

    for (int k0 = 0; k0 < K; k0 += 32) {
        {
            const float* s = X + (size_t)(m0 + ar) * K + k0 + ah * 16;
            us8_t t0, t1;
            {
                float4 v = *(const float4*)(s + 0);
                t0[0] = f2bf(v.x); t0[1] = f2bf(v.y); t0[2] = f2bf(v.z); t0[3] = f2bf(v.w);
                float4 w = *(const float4*)(s + 4);
                t0[4] = f2bf(w.x); t0[5] = f2bf(w.y); t0[6] = f2bf(w.z); t0[7] = f2bf(w.w);
            }
            {
                float4 v = *(const float4*)(s + 8);
                t1[0] = f2bf(v.x); t1[1] = f2bf(v.y); t1[2] = f2bf(v.z); t1[3] = f2bf(v.w);
                float4 w = *(const float4*)(s + 12);
                t1[4] = f2bf(w.x); t1[5] = f2bf(w.y); t1[6] = f2bf(w.z); t1[7] = f2bf(w.w);
            }
            *(us8_t*)&As[ar * 32 + ah * 16 + 0] = t0;
            *(us8_t*)&As[ar * 32 + ah * 16 + 8] = t1;
        }
        {
            const u16* s = W + (size_t)(n0 + br) * K + k0 + bc * 8;
            *(us8_t*)&Bs[br * 32 + bc * 8] = *(const us8_t*)s;
        }
        __syncthreads();
        bf16x8_t af[4], bfr[2];
        for (int i = 0; i < 4; i++) af[i] = ld_bf8(&As[(wm + i * 16 + l15) * 32 + quad * 8]);
        for (int j = 0; j < 2; j++) bfr[j] = ld_bf8(&Bs[(wn + j * 16 + l15) * 32 + quad * 8]);
        for (int i = 0; i < 4; i++)
            for (int j = 0; j < 2; j++)
                acc[i][j] = mfma16(af[i], bfr[j], acc[i][j]);
        __syncthreads();
    }

    for (int i = 0; i < 4; i++) {
        const int gmb = m0 + wm + i * 16 + quad * 4;
        for (int j = 0; j < 2; j++) {
            const int gn = n0 + wn + j * 16 + l15;
            const float bb = bias[gn];
            if (z < 2) {
                u16* Y = (z == 0) ? Qo : Ko;
                for (int r = 0; r < 4; r++)
                    Y[(size_t)(gmb + r) * 1024 + gn] = f2bf(acc[i][j][r] + bb);
            } else {
                // transposed store into Vt[bh][d][s]: flat = (b*1024+gn)*2048 + s
                const int bb_idx = gmb >> 11, s = gmb & 2047;
                us4_t w;
                for (int r = 0; r < 4; r++) w[r] = f2bf(acc[i][j][r] + bb);
                *(us4_t*)&Vo[((size_t)(bb_idx * 1024 + gn)) * 2048 + s] = w;
            }
        }
    }
}

// ---------------- output projection GEMM: out[4096,1024] = CT @ Wo^T + bo ----------------
__global__ __launch_bounds__(256) void out_gemm_kernel(
    const u16* __restrict__ X, const u16* __restrict__ Wt,
    const float* __restrict__ bias, float* __restrict__ Y)
{
    constexpr int K = 1024;
    __shared__ u16 As[128 * 32];
    __shared__ u16 Bs[64 * 32];
    const int m0 = blockIdx.x * 128, n0 = blockIdx.y * 64;
    const int tid = threadIdx.x;
    const int lane = tid & 63, wave = tid >> 6;
    const int l15 = lane & 15, quad = lane >> 4;
    const int wm = (wave & 1) * 64, wn = (wave >> 1) * 32;

    const f32x4_t z4 = {0.f, 0.f, 0.f, 0.f};
    f32x4_t acc[4][2];
    for (int i = 0; i < 4; i++) for (int j = 0; j < 2; j++) acc[i][j] = z4;

    const int ar = tid >> 1, ah = tid & 1;
    const int br = tid >> 2, bc = tid & 3;

    for (int k0 = 0; k0 < K; k0 += 32) {
        {
            const u16* s = X + (size_t)(m0 + ar) * K + k0 + ah * 16;
            *(us8_t*)&As[ar * 32 + ah * 16 + 0] = *(const us8_t*)(s + 0);
            *(us8_t*)&As[ar * 32 + ah * 16 + 8] = *(const us8_t*)(s + 8);
        }
        {
            const u16* s = Wt + (size_t)(n0 + br) * K + k0 + bc * 8;
            *(us8_t*)&Bs[br * 32 + bc * 8] = *(const us8_t*)s;
        }
        __syncthreads();
        bf16x8_t af[4], bfr[2];
        for (int i = 0; i < 4; i++) af[i] = ld_bf8(&As[(wm + i * 16 + l15) * 32 + quad * 8]);
        for (int j = 0; j < 2; j++) bfr[j] = ld_bf8(&Bs[(wn + j * 16 + l15) * 32 + quad * 8]);
        for (int i = 0; i < 4; i++)
            for (int j = 0; j < 2; j++)
                acc[i][j] = mfma16(af[i], bfr[j], acc[i][j]);
        __syncthreads();
    }

    for (int i = 0; i < 4; i++) {
        const int gmb = m0 + wm + i * 16 + quad * 4;
        for (int j = 0; j < 2; j++) {
            const int gn = n0 + wn + j * 16 + l15;
            const float bb = bias[gn];
            for (int r = 0; r < 4; r++)
                Y[(size_t)(gmb + r) * 1024 + gn] = acc[i][j][r] + bb;
        }
    }
}

// ---------------- flash attention v2 ----------------
// grid: (h=16, qb=32, b=2), 256 thr = 4 independent waves, wave = 16 q rows.
// 128-key tiles; NO __syncthreads (P round-trip is wave-private; DS pipe is
// in-order per wave; explicit lgkmcnt(0)+wave_barrier orders write->read).
__global__ __launch_bounds__(256) void attn_kernel(
    const u16* __restrict__ Q, const u16* __restrict__ Kb,
    const u16* __restrict__ Vt, const unsigned* __restrict__ mp,
    u16* __restrict__ C)
{
    const int h = blockIdx.x, qb = blockIdx.y, b = blockIdx.z;
    const int tid = threadIdx.x, lane = tid & 63, wave = tid >> 6;
    const int l15 = lane & 15, quad = lane >> 4;
    const int q0 = qb * 64 + wave * 16;
    const int grow = b * 2048 + q0;

    // per-wave P staging: 4 chunks x 16 rows x 32 u16, group XOR-swizzled by row-quad
    __shared__ u16 Pl[4][2048];

    bf16x8_t aq[2];
    for (int ks = 0; ks < 2; ks++)
        aq[ks] = ld_bf8(Q + (size_t)(grow + l15) * 1024 + h * 64 + ks * 32 + quad * 8);

    const f32x4_t z4 = {0.f, 0.f, 0.f, 0.f};
    f32x4_t o[4];
    for (int i = 0; i < 4; i++) o[i] = z4;
    float mrow[4], lrow[4];
    for (int r = 0; r < 4; r++) { mrow[r] = -__builtin_inff(); lrow[r] = 0.f; }

    const u16* Kbase = Kb + (size_t)(b * 2048) * 1024 + h * 64;
    const u16* Vbase = Vt + ((size_t)(b * 16 + h) * 64) * 2048;
    const unsigned* mbase = mp + (size_t)(b * 2048 + q0 + quad * 4) * 64;

    const int gr = quad ^ (l15 >> 2);   // read-side swizzled group

    for (int kt = 0; kt < 16; ++kt) {
        const int kbase = kt * 128;

        // QK^T: 8 score tiles (16q x 16k each), K=64 -> 2 MFMAs per tile
        f32x4_t sc[8];
        #pragma unroll
        for (int s = 0; s < 8; s++) {
            const u16* kp = Kbase + (size_t)(kbase + s * 16 + l15) * 1024 + quad * 8;
            bf16x8_t b0 = ld_bf8(kp);
            bf16x8_t b1 = ld_bf8(kp + 32);
            f32x4_t t = mfma16(aq[0], b0, z4);
            sc[s] = mfma16(aq[1], b1, t);
        }

        // online softmax over 128 keys, one reduction tree per row
        #pragma unroll
        for (int r = 0; r < 4; r++) {
            const unsigned* mpr = mbase + r * 64 + kt * 4;
            const unsigned mw0 = mpr[0], mw1 = mpr[1], mw2 = mpr[2], mw3 = mpr[3];
            float vv[8];
            #pragma unroll
            for (int s = 0; s < 8; s++) {
                const unsigned mw = (s < 2) ? mw0 : (s < 4) ? mw1 : (s < 6) ? mw2 : mw3;
                const float x = sc[s][r] * 0.125f;
                vv[s] = ((mw >> (((s & 1) << 4) + l15)) & 1u) ? x - 1e9f : x;
            }
            float x = fmaxf(fmaxf(fmaxf(vv[0], vv[1]), fmaxf(vv[2], vv[3])),
                            fmaxf(fmaxf(vv[4], vv[5]), fmaxf(vv[6], vv[7])));
            #pragma unroll
            for (int off = 1; off < 16; off <<= 1) x = fmaxf(x, __shfl_xor(x, off));
            const float mnew = fmaxf(mrow[r], x);
            const float alpha = __expf(mrow[r] - mnew);
            float p[8], ssum = 0.f;
            #pragma unroll
            for (int s = 0; s < 8; s++) { p[s] = __expf(vv[s] - mnew); ssum += p[s]; }
            #pragma unroll
            for (int off = 1; off < 16; off <<= 1) ssum += __shfl_xor(ssum, off);
            mrow[r] = mnew;
            lrow[r] = lrow[r] * alpha + ssum;
            #pragma unroll
            for (int nt = 0; nt < 4; nt++) o[nt][r] *= alpha;
            const int prow = (quad * 4 + r) * 32;
            #pragma unroll
            for (int s = 0; s < 8; s++) {
                const int g = (((s & 1) << 1) | (l15 >> 3)) ^ quad;
                Pl[wave][(s >> 1) * 512 + prow + g * 8 + (l15 & 7)] = f2bf(p[s]);
            }
        }

        // order P writes before P reads (wave-private, no __syncthreads needed)
        __builtin_amdgcn_wave_barrier();
        __builtin_amdgcn_s_waitcnt(0xC07F);   // lgkmcnt(0)
        __builtin_amdgcn_wave_barrier();

        // PV: P(16x128) x V(128x64)
        #pragma unroll
        for (int c = 0; c < 4; c++) {
            bf16x8_t ap = ld_bf8(&Pl[wave][c * 512 + l15 * 32 + gr * 8]);
            #pragma unroll
            for (int nt = 0; nt < 4; nt++) {
                bf16x8_t bv2 = ld_bf8(Vbase + (size_t)(nt * 16 + l15) * 2048 + kbase + c * 32 + quad * 8);
                o[nt] = mfma16(ap, bv2, o[nt]);
            }
        }
        __builtin_amdgcn_wave_barrier();
    }

    for (int r = 0; r < 4; r++) {
        const float invl = 1.0f / lrow[r];
        for (int nt = 0; nt < 4; nt++)
            C[(size_t)(grow + quad * 4 + r) * 1024 + h * 64 + nt * 16 + l15] = f2bf(o[nt][r] * invl);
    }
}

extern "C" void kernel_launch(void* const* d_in, const int* in_sizes, int n_in,
                              void* d_out, int out_size, void* d_ws, size_t ws_size,
                              hipStream_t stream) {
    const float* q    = (const float*)d_in[0];
    const float* k    = (const float*)d_in[1];
    const float* v    = (const float*)d_in[2];
    const int*   mask = (const int*)d_in[3];
    const float* wq   = (const float*)d_in[4];
    const float* bq   = (const float*)d_in[5];
    const float* wk   = (const float*)d_in[6];
    const float* bk   = (const float*)d_in[7];
    const float* wv   = (const float*)d_in[8];
    const float* bv   = (const float*)d_in[9];
    const float* wo   = (const float*)d_in[10];
    const float* bo   = (const float*)d_in[11];
    float* out = (float*)d_out;

    char* ws = (char*)d_ws;
    const size_t MB = 1ull << 20;
    u16* Wt      = (u16*)(ws);             // 4 x 2 MB (bf16 [n][k] per weight)
    u16* Qb      = (u16*)(ws + 8 * MB);    // 8 MB
    u16* Kbw     = (u16*)(ws + 16 * MB);   // 8 MB
    u16* Vtw     = (u16*)(ws + 24 * MB);   // 8 MB (transposed [bh][d][s])
    u16* CT      = (u16*)(ws + 32 * MB);   // 8 MB
    unsigned* mp = (unsigned*)(ws + 40 * MB); // 1 MB

    transpose_w_kernel<<<dim3(16, 16, 4), 256, 0, stream>>>(wq, wk, wv, wo, Wt);
    pack_mask_kernel<<<dim3(1024), 256, 0, stream>>>(mask, mp);

    qkv_gemm_kernel<<<dim3(32, 16, 3), 256, 0, stream>>>(
        q, k, v, Wt, bq, bk, bv, Qb, Kbw, Vtw);

    attn_kernel<<<dim3(16, 32, 2), 256, 0, stream>>>(Qb, Kbw, Vtw, mp, CT);

    out_gemm_kernel<<<dim3(32, 16), 256, 0, stream>>>(CT, Wt + 3ull * 1024 * 1024, bo, out);
}

// Round 3
// 306.828 us; speedup vs baseline: 1.6515x; 1.5526x over previous
//
#include <hip/hip_runtime.h>

typedef unsigned short u16;
typedef __bf16 bf16x8_t __attribute__((ext_vector_type(8)));
typedef float  f32x4_t  __attribute__((ext_vector_type(4)));
typedef u16    us8_t    __attribute__((ext_vector_type(8)));
typedef u16    us4_t    __attribute__((ext_vector_type(4)));

__device__ __forceinline__ u16 f2bf(float f) {
    __bf16 h = (__bf16)f;
    return __builtin_bit_cast(u16, h);
}
__device__ __forceinline__ bf16x8_t ld_bf8(const u16* p) {
    us8_t u = *(const us8_t*)p;
    return __builtin_bit_cast(bf16x8_t, u);
}
__device__ __forceinline__ f32x4_t mfma16(bf16x8_t a, bf16x8_t b, f32x4_t c) {
    return __builtin_amdgcn_mfma_f32_16x16x32_bf16(a, b, c, 0, 0, 0);
}

// async global->LDS, 16B per lane. LDS dest MUST be base + lane*16 (wave-uniform base).
__device__ __forceinline__ void dma16(const u16* g, u16* l) {
#if __has_builtin(__builtin_amdgcn_global_load_lds)
    __builtin_amdgcn_global_load_lds((const __attribute__((address_space(1))) unsigned int*)(g),
                                     (__attribute__((address_space(3))) unsigned int*)(l), 16, 0, 0);
#else
    *(us8_t*)l = *(const us8_t*)g;
#endif
}

// ---------------- fp32 -> bf16 convert (q,k,v inputs) ----------------
__global__ __launch_bounds__(256) void cvt_kernel(
    const float* __restrict__ q, const float* __restrict__ k, const float* __restrict__ v,
    u16* __restrict__ Qc, u16* __restrict__ Kc, u16* __restrict__ Vc)
{
    const int z = blockIdx.y;
    const float* src = (z == 0) ? q : (z == 1) ? k : v;
    u16* dst = (z == 0) ? Qc : (z == 1) ? Kc : Vc;
    const size_t i = ((size_t)blockIdx.x * 256 + threadIdx.x) * 8;
    float4 a = *(const float4*)(src + i);
    float4 b = *(const float4*)(src + i + 4);
    us8_t w;
    w[0] = f2bf(a.x); w[1] = f2bf(a.y); w[2] = f2bf(a.z); w[3] = f2bf(a.w);
    w[4] = f2bf(b.x); w[5] = f2bf(b.y); w[6] = f2bf(b.z); w[7] = f2bf(b.w);
    *(us8_t*)(dst + i) = w;
}

// ---------------- weight transpose+convert: fp32 [k][n] -> bf16 [n][k] ----------------
__global__ __launch_bounds__(256) void transpose_w_kernel(
    const float* __restrict__ w0, const float* __restrict__ w1,
    const float* __restrict__ w2, const float* __restrict__ w3,
    u16* __restrict__ out)
{
    __shared__ u16 t[64][65];
    const int z = blockIdx.z;
    const float* src = (z == 0) ? w0 : (z == 1) ? w1 : (z == 2) ? w2 : w3;
    u16* dst = out + (size_t)z * 1024 * 1024;
    const int bk = blockIdx.x * 64, bn = blockIdx.y * 64;
    const int tid = threadIdx.x;
    const int r = tid >> 2, c4 = tid & 3;
    for (int i = 0; i < 4; i++) {
        float4 v = *(const float4*)(src + (size_t)(bk + r) * 1024 + bn + c4 * 16 + i * 4);
        t[r][c4 * 16 + i * 4 + 0] = f2bf(v.x);
        t[r][c4 * 16 + i * 4 + 1] = f2bf(v.y);
        t[r][c4 * 16 + i * 4 + 2] = f2bf(v.z);
        t[r][c4 * 16 + i * 4 + 3] = f2bf(v.w);
    }
    __syncthreads();
    for (int i = 0; i < 2; i++) {
        us8_t w;
        for (int j = 0; j < 8; j++) w[j] = t[c4 * 16 + i * 8 + j][r];
        *(us8_t*)(dst + (size_t)(bn + r) * 1024 + bk + c4 * 16 + i * 8) = w;
    }
}

// ---------------- mask pack: int32 [B,1,S,S] -> 1 bit per key ----------------
__global__ __launch_bounds__(256) void pack_mask_kernel(
    const int* __restrict__ mask, unsigned* __restrict__ mp)
{
    const int w = blockIdx.x * 256 + threadIdx.x;
    const int* src = mask + (size_t)w * 32;
    unsigned bits = 0u;
    for (int i = 0; i < 32; i += 4) {
        int4 v = *(const int4*)(src + i);
        bits |= (unsigned)(v.x != 0) << (i + 0);
        bits |= (unsigned)(v.y != 0) << (i + 1);
        bits |= (unsigned)(v.z != 0) << (i + 2);
        bits |= (unsigned)(v.w != 0) << (i + 3);
    }
    mp[w] = bits;
}

// ---------------- fused QKV projection GEMM (m97-style, DMA staging) ----------------
// 128x128 tile, BK=32. z=0: Q -> head-major swizzled; z=1: K same; z=2: V -> tiled swizzled Vt.
// Swizzle: within a 64-u16 (128B) row, 16B chunk j stored at j ^ (row&7). For Vt rows are d
// (128 u16 = 256B), chunk j (0..15) stored at j ^ (d&7).
__global__ __launch_bounds__(256) void qkv_gemm_kernel(
    const u16* __restrict__ Qc, const u16* __restrict__ Kc, const u16* __restrict__ Vc,
    const u16* __restrict__ Wt,
    const float* __restrict__ bq, const float* __restrict__ bk, const float* __restrict__ bv,
    u16* __restrict__ Qh, u16* __restrict__ Kh, u16* __restrict__ Vtt)
{
    __shared__ __align__(16) u16 As[4096];
    __shared__ __align__(16) u16 Bs[4096];
    const int z = blockIdx.z;
    const u16* A = (z == 0) ? Qc : (z == 1) ? Kc : Vc;
    const u16* W = Wt + (size_t)z * 1048576;
    const float* bias = (z == 0) ? bq : (z == 1) ? bk : bv;

    const int m0 = blockIdx.x * 128, n0 = blockIdx.y * 128;
    const int tid = threadIdx.x, lane = tid & 63, wave = tid >> 6;
    const int l15 = lane & 15, quad = lane >> 4;
    const int wm = (wave & 1) * 64, wn = (wave >> 1) * 64;
    const int srow = lane >> 2, scol = (lane & 3) * 8;

    const f32x4_t z4 = {0.f, 0.f, 0.f, 0.f};
    f32x4_t acc[4][4];
    for (int i = 0; i < 4; i++) for (int j = 0; j < 4; j++) acc[i][j] = z4;

    for (int k0 = 0; k0 < 1024; k0 += 32) {
        #pragma unroll
        for (int i = 0; i < 2; i++) {
            dma16(A + (size_t)(m0 + wave * 32 + i * 16 + srow) * 1024 + k0 + scol,
                  &As[wave * 1024 + i * 512 + lane * 8]);
            dma16(W + (size_t)(n0 + wave * 32 + i * 16 + srow) * 1024 + k0 + scol,
                  &Bs[wave * 1024 + i * 512 + lane * 8]);
        }
        __syncthreads();
        bf16x8_t af[4], bfr[4];
        #pragma unroll
        for (int i = 0; i < 4; i++) af[i] = ld_bf8(&As[(wm + i * 16 + l15) * 32 + quad * 8]);
        #pragma unroll
        for (int j = 0; j < 4; j++) bfr[j] = ld_bf8(&Bs[(wn + j * 16 + l15) * 32 + quad * 8]);
        #pragma unroll
        for (int i = 0; i < 4; i++)
            #pragma unroll
            for (int j = 0; j < 4; j++)
                acc[i][j] = mfma16(af[i], bfr[j], acc[i][j]);
        __syncthreads();
    }

    #pragma unroll
    for (int i = 0; i < 4; i++) {
        const int m = m0 + wm + i * 16 + quad * 4;
        #pragma unroll
        for (int j = 0; j < 4; j++) {
            const int gn = n0 + wn + j * 16 + l15;
            const float bb = bias[gn];
            const int h = gn >> 6, dh = gn & 63;
            if (z < 2) {
                u16* Y = z ? Kh : Qh;
                const int jc = dh >> 3, e = dh & 7;
                #pragma unroll
                for (int r = 0; r < 4; r++) {
                    const int mm = m + r;
                    const int b = mm >> 11, s = mm & 2047;
                    Y[((size_t)(b * 16 + h) * 2048 + s) * 64 + ((jc ^ (s & 7)) * 8) + e] =
                        f2bf(acc[i][j][r] + bb);
                }
            } else {
                const int b = m >> 11, sh = m & 2047, kt = sh >> 7, sl = sh & 127;
                const int jc = sl >> 3;
                us4_t w4;
                #pragma unroll
                for (int r = 0; r < 4; r++) w4[r] = f2bf(acc[i][j][r] + bb);
                size_t off = ((((size_t)(b * 16 + h) * 16 + kt) * 64 + dh) * 128)
                           + (size_t)((jc ^ (dh & 7)) * 8 + (sl & 7));
                *(us4_t*)&Vtt[off] = w4;
            }
        }
    }
}

// ---------------- output projection GEMM (m97-style): out = CT @ Wo^T + bo (fp32) ----------
__global__ __launch_bounds__(256) void out_gemm_kernel(
    const u16* __restrict__ X, const u16* __restrict__ Wt,
    const float* __restrict__ bias, float* __restrict__ Y)
{
    __shared__ __align__(16) u16 As[4096];
    __shared__ __align__(16) u16 Bs[4096];
    const int m0 = blockIdx.x * 128, n0 = blockIdx.y * 128;
    const int tid = threadIdx.x, lane = tid & 63, wave = tid >> 6;
    const int l15 = lane & 15, quad = lane >> 4;
    const int wm = (wave & 1) * 64, wn = (wave >> 1) * 64;
    const int srow = lane >> 2, scol = (lane & 3) * 8;

    const f32x4_t z4 = {0.f, 0.f, 0.f, 0.f};
    f32x4_t acc[4][4];
    for (int i = 0; i < 4; i++) for (int j = 0; j < 4; j++) acc[i][j] = z4;

    for (int k0 = 0; k0 < 1024; k0 += 32) {
        #pragma unroll
        for (int i = 0; i < 2; i++) {
            dma16(X + (size_t)(m0 + wave * 32 + i * 16 + srow) * 1024 + k0 + scol,
                  &As[wave * 1024 + i * 512 + lane * 8]);
            dma16(Wt + (size_t)(n0 + wave * 32 + i * 16 + srow) * 1024 + k0 + scol,
                  &Bs[wave * 1024 + i * 512 + lane * 8]);
        }
        __syncthreads();
        bf16x8_t af[4], bfr[4];
        #pragma unroll
        for (int i = 0; i < 4; i++) af[i] = ld_bf8(&As[(wm + i * 16 + l15) * 32 + quad * 8]);
        #pragma unroll
        for (int j = 0; j < 4; j++) bfr[j] = ld_bf8(&Bs[(wn + j * 16 + l15) * 32 + quad * 8]);
        #pragma unroll
        for (int i = 0; i < 4; i++)
            #pragma unroll
            for (int j = 0; j < 4; j++)
                acc[i][j] = mfma16(af[i], bfr[j], acc[i][j]);
        __syncthreads();
    }

    #pragma unroll
    for (int i = 0; i < 4; i++) {
        const int m = m0 + wm + i * 16 + quad * 4;
        #pragma unroll
        for (int j = 0; j < 4; j++) {
            const int gn = n0 + wn + j * 16 + l15;
            const float bb = bias[gn];
            #pragma unroll
            for (int r = 0; r < 4; r++)
                Y[(size_t)(m + r) * 1024 + gn] = acc[i][j][r] + bb;
        }
    }
}

// ---------------- flash attention v3: LDS-staged K/V via DMA ----------------
// grid (qb=32, h=16, b=2) — qb fastest so each XCD keeps one head's K/V in L2.
// Per block: 4 waves x 16 q rows; 128-key tiles; K tile 128x64 (swizzled rows, 16KB),
// V tile 64x128 transposed (swizzled, 16KB). P aliases the K tile (dead after QK reads).
__global__ __launch_bounds__(256) void attn_kernel(
    const u16* __restrict__ Qh, const u16* __restrict__ Kh,
    const u16* __restrict__ Vtt, const unsigned* __restrict__ mp,
    u16* __restrict__ C)
{
    __shared__ __align__(16) u16 KP[8192];   // K tile; re-used as P (wave*2048) after QK
    __shared__ __align__(16) u16 Vs[8192];   // V tile (transposed)
    const int qb = blockIdx.x, h = blockIdx.y, b = blockIdx.z;
    const int tid = threadIdx.x, lane = tid & 63, wave = tid >> 6;
    const int l15 = lane & 15, quad = lane >> 4;
    const int q0 = qb * 64 + wave * 16;
    const int grow = b * 2048 + q0;
    const size_t headoff = (size_t)(b * 16 + h) * 131072;

    const u16* Qg = Qh + headoff;
    const u16* Kg = Kh + headoff;
    const u16* Vg = Vtt + headoff;

    bf16x8_t aq[2];
    #pragma unroll
    for (int ks = 0; ks < 2; ks++)
        aq[ks] = ld_bf8(Qg + (size_t)(q0 + l15) * 64 + (((ks * 4 + quad) ^ (l15 & 7)) * 8));

    const f32x4_t z4 = {0.f, 0.f, 0.f, 0.f};
    f32x4_t o[4];
    for (int i = 0; i < 4; i++) o[i] = z4;
    float mrow[4], lrow[4];
    for (int r = 0; r < 4; r++) { mrow[r] = -__builtin_inff(); lrow[r] = 0.f; }

    const unsigned* mbase = mp + (size_t)(b * 2048 + q0 + quad * 4) * 64;
    u16* Pw = &KP[wave * 2048];
    const int gr = quad ^ (l15 >> 2);

    const int halfo = (wave & 1) * 4096;
    const u16* gsrc0 = (wave & 2) ? Vg : Kg;
    u16* lst0 = (wave & 2) ? Vs : KP;

    for (int kt = 0; kt < 16; ++kt) {
        // --- DMA this tile's K and V (32KB total, 8 x 1KB per wave) ---
        const u16* gsrc = gsrc0 + kt * 8192 + halfo;
        u16* lst = lst0 + halfo;
        #pragma unroll
        for (int i = 0; i < 8; i++)
            dma16(gsrc + i * 512 + lane * 8, lst + i * 512 + lane * 8);
        __syncthreads();

        // --- QK^T from LDS (swizzled, conflict-free) ---
        f32x4_t sc[8];
        #pragma unroll
        for (int st = 0; st < 8; st++) {
            const u16* kp = &KP[(st * 16 + l15) * 64];
            bf16x8_t b0 = ld_bf8(kp + ((quad ^ (l15 & 7)) * 8));
            bf16x8_t b1 = ld_bf8(kp + (((4 + quad) ^ (l15 & 7)) * 8));
            f32x4_t t = mfma16(aq[0], b0, z4);
            sc[st] = mfma16(aq[1], b1, t);
        }
        __syncthreads();   // all waves done reading K -> P may overwrite KP

        // --- online softmax over 128 keys ---
        #pragma unroll
        for (int r = 0; r < 4; r++) {
            const unsigned* mpr = mbase + r * 64 + kt * 4;
            const unsigned mw0 = mpr[0], mw1 = mpr[1], mw2 = mpr[2], mw3 = mpr[3];
            float vv[8];
            #pragma unroll
            for (int s = 0; s < 8; s++) {
                const unsigned mw = (s < 2) ? mw0 : (s < 4) ? mw1 : (s < 6) ? mw2 : mw3;
                const float x = sc[s][r] * 0.125f;
                vv[s] = ((mw >> (((s & 1) << 4) + l15)) & 1u) ? x - 1e9f : x;
            }
            float x = fmaxf(fmaxf(fmaxf(vv[0], vv[1]), fmaxf(vv[2], vv[3])),
                            fmaxf(fmaxf(vv[4], vv[5]), fmaxf(vv[6], vv[7])));
            #pragma unroll
            for (int off = 1; off < 16; off <<= 1) x = fmaxf(x, __shfl_xor(x, off));
            const float mnew = fmaxf(mrow[r], x);
            const float alpha = __expf(mrow[r] - mnew);
            float p[8], ssum = 0.f;
            #pragma unroll
            for (int s = 0; s < 8; s++) { p[s] = __expf(vv[s] - mnew); ssum += p[s]; }
            #pragma unroll
            for (int off = 1; off < 16; off <<= 1) ssum += __shfl_xor(ssum, off);
            mrow[r] = mnew;
            lrow[r] = lrow[r] * alpha + ssum;
            #pragma unroll
            for (int nt = 0; nt < 4; nt++) o[nt][r] *= alpha;
            const int prow = (quad * 4 + r) * 32;
            #pragma unroll
            for (int s = 0; s < 8; s++) {
                const int g = (((s & 1) << 1) | (l15 >> 3)) ^ quad;
                Pw[(s >> 1) * 512 + prow + g * 8 + (l15 & 7)] = f2bf(p[s]);
            }
        }

        // wave-local ordering of P writes before P reads
        __builtin_amdgcn_wave_barrier();
        __builtin_amdgcn_s_waitcnt(0xC07F);   // lgkmcnt(0)
        __builtin_amdgcn_wave_barrier();

        // --- PV from LDS V tile ---
        #pragma unroll
        for (int c = 0; c < 4; c++) {
            bf16x8_t ap = ld_bf8(&Pw[c * 512 + l15 * 32 + gr * 8]);
            #pragma unroll
            for (int nt = 0; nt < 4; nt++) {
                const u16* vp = &Vs[(nt * 16 + l15) * 128 + (((c * 4 + quad) ^ (l15 & 7)) * 8)];
                o[nt] = mfma16(ap, ld_bf8(vp), o[nt]);
            }
        }
        __syncthreads();   // protect KP/Vs (and P region) before next tile's DMA
    }

    #pragma unroll
    for (int r = 0; r < 4; r++) {
        const float invl = 1.0f / lrow[r];
        #pragma unroll
        for (int nt = 0; nt < 4; nt++)
            C[(size_t)(grow + quad * 4 + r) * 1024 + h * 64 + nt * 16 + l15] = f2bf(o[nt][r] * invl);
    }
}

extern "C" void kernel_launch(void* const* d_in, const int* in_sizes, int n_in,
                              void* d_out, int out_size, void* d_ws, size_t ws_size,
                              hipStream_t stream) {
    const float* q    = (const float*)d_in[0];
    const float* k    = (const float*)d_in[1];
    const float* v    = (const float*)d_in[2];
    const int*   mask = (const int*)d_in[3];
    const float* wq   = (const float*)d_in[4];
    const float* bq   = (const float*)d_in[5];
    const float* wk   = (const float*)d_in[6];
    const float* bk   = (const float*)d_in[7];
    const float* wv   = (const float*)d_in[8];
    const float* bv   = (const float*)d_in[9];
    const float* wo   = (const float*)d_in[10];
    const float* bo   = (const float*)d_in[11];
    float* out = (float*)d_out;

    char* ws = (char*)d_ws;
    const size_t MB = 1ull << 20;
    u16* Wt      = (u16*)(ws);              // 8 MB: 4 weights bf16 [n][k]
    u16* Qc      = (u16*)(ws + 8 * MB);     // 8 MB bf16 input q
    u16* Kc      = (u16*)(ws + 16 * MB);    // 8 MB bf16 input k
    u16* Vc      = (u16*)(ws + 24 * MB);    // 8 MB bf16 input v
    u16* Qh      = (u16*)(ws + 32 * MB);    // 8 MB head-major swizzled
    u16* Kh      = (u16*)(ws + 40 * MB);    // 8 MB head-major swizzled
    u16* Vtt     = (u16*)(ws + 48 * MB);    // 8 MB tiled transposed swizzled
    u16* CT      = (u16*)(ws + 8 * MB);     // reuse Qc (dead after qkv_gemm)
    unsigned* mp = (unsigned*)(ws + 56 * MB); // 1 MB

    cvt_kernel<<<dim3(2048, 3), 256, 0, stream>>>(q, k, v, Qc, Kc, Vc);
    transpose_w_kernel<<<dim3(16, 16, 4), 256, 0, stream>>>(wq, wk, wv, wo, Wt);
    pack_mask_kernel<<<dim3(1024), 256, 0, stream>>>(mask, mp);

    qkv_gemm_kernel<<<dim3(32, 8, 3), 256, 0, stream>>>(
        Qc, Kc, Vc, Wt, bq, bk, bv, Qh, Kh, Vtt);

    attn_kernel<<<dim3(32, 16, 2), 256, 0, stream>>>(Qh, Kh, Vtt, mp, CT);

    out_gemm_kernel<<<dim3(32, 8), 256, 0, stream>>>(CT, Wt + 3ull * 1048576, bo, out);
}